// Round 1
// baseline (44.373 us; speedup 1.0000x reference)
//
#include <hip/hip_runtime.h>
#include <math.h>

#define N_RAYS 65536
#define N_SAMPLES 256
#define T_THRESHOLD 1e-4f
#define NEAR_DISTANCE 0.01f

// One 64-lane wave per ray. Lane l handles samples [4l, 4l+4).
__global__ __launch_bounds__(256) void ngp_render_kernel(
    const float* __restrict__ rays,      // [N_RAYS, 6]
    const float* __restrict__ sigmas,    // [N_RAYS, N_SAMPLES]
    const float* __restrict__ rgbs,      // [N_RAYS, N_SAMPLES, 3]
    const float* __restrict__ center,    // [3]
    const float* __restrict__ half_size, // [3]
    float* __restrict__ out)             // [N_RAYS, 3]
{
    const int gtid = blockIdx.x * blockDim.x + threadIdx.x;
    const int ray  = gtid >> 6;          // wave index == ray index
    const int lane = threadIdx.x & 63;
    if (ray >= N_RAYS) return;

    // ---- ray setup: every lane computes the same (broadcast loads) ----
    const float* rp = rays + (size_t)ray * 6;
    float o[3] = { rp[0], rp[1], rp[2] };
    float d[3] = { rp[3], rp[4], rp[5] };
    float inv_norm = 1.0f / (sqrtf(d[0]*d[0] + d[1]*d[1] + d[2]*d[2]) + 1e-8f);
    d[0] *= inv_norm; d[1] *= inv_norm; d[2] *= inv_norm;

    float tmin = -INFINITY, tmax = INFINITY;
    #pragma unroll
    for (int a = 0; a < 3; ++a) {
        float da  = (fabsf(d[a]) > 1e-8f) ? d[a] : 1e-8f;
        float inv = 1.0f / da;
        float t1  = (center[a] - half_size[a] - o[a]) * inv;
        float t2  = (center[a] + half_size[a] - o[a]) * inv;
        tmin = fmaxf(tmin, fminf(t1, t2));
        tmax = fminf(tmax, fmaxf(t1, t2));
    }
    const bool hit = tmax > fmaxf(tmin, 0.0f);
    float near = fmaxf(tmin, 0.0f);
    if (hit && near < NEAR_DISTANCE) near = NEAR_DISTANCE;
    const float far   = hit ? tmax : near;
    const float delta = (far - near) * (1.0f / (float)N_SAMPLES);

    // ---- sigma * delta, local prefix over 4 samples ----
    const float4 sg = *reinterpret_cast<const float4*>(
        sigmas + (size_t)ray * N_SAMPLES + lane * 4);
    const float sd0 = sg.x * delta;
    const float sd1 = sg.y * delta;
    const float sd2 = sg.z * delta;
    const float sd3 = sg.w * delta;
    const float p0 = sd0;
    const float p1 = p0 + sd1;
    const float p2 = p1 + sd2;
    const float p3 = p2 + sd3;        // lane total

    // ---- wave-inclusive scan of lane totals (6 shfl_up steps) ----
    float incl = p3;
    #pragma unroll
    for (int off = 1; off < 64; off <<= 1) {
        float v = __shfl_up(incl, off, 64);
        if (lane >= off) incl += v;
    }
    const float excl = incl - p3;     // exclusive prefix entering this lane

    // ---- transmittance, alpha, weights ----
    const float T0 = expf(-excl);
    const float T1 = expf(-(excl + p0));
    const float T2 = expf(-(excl + p1));
    const float T3 = expf(-(excl + p2));
    const float a0 = 1.0f - expf(-sd0);
    const float a1 = 1.0f - expf(-sd1);
    const float a2 = 1.0f - expf(-sd2);
    const float a3 = 1.0f - expf(-sd3);
    const float ws0 = (hit && T0 >= T_THRESHOLD) ? a0 * T0 : 0.0f;
    const float ws1 = (hit && T1 >= T_THRESHOLD) ? a1 * T1 : 0.0f;
    const float ws2 = (hit && T2 >= T_THRESHOLD) ? a2 * T2 : 0.0f;
    const float ws3 = (hit && T3 >= T_THRESHOLD) ? a3 * T3 : 0.0f;

    // ---- rgbs: 48 contiguous bytes per lane, 3 aligned float4 loads ----
    const float* rb = rgbs + (size_t)ray * N_SAMPLES * 3 + (size_t)lane * 12;
    const float4 r0 = *reinterpret_cast<const float4*>(rb + 0);
    const float4 r1 = *reinterpret_cast<const float4*>(rb + 4);
    const float4 r2 = *reinterpret_cast<const float4*>(rb + 8);
    // sample 4l+0 -> (r0.x, r0.y, r0.z)
    // sample 4l+1 -> (r0.w, r1.x, r1.y)
    // sample 4l+2 -> (r1.z, r1.w, r2.x)
    // sample 4l+3 -> (r2.y, r2.z, r2.w)
    float R = ws0 * r0.x + ws1 * r0.w + ws2 * r1.z + ws3 * r2.y;
    float G = ws0 * r0.y + ws1 * r1.x + ws2 * r1.w + ws3 * r2.z;
    float B = ws0 * r0.z + ws1 * r1.y + ws2 * r2.x + ws3 * r2.w;

    // ---- wave reduce ----
    #pragma unroll
    for (int off = 32; off > 0; off >>= 1) {
        R += __shfl_xor(R, off, 64);
        G += __shfl_xor(G, off, 64);
        B += __shfl_xor(B, off, 64);
    }
    if (lane == 0) {
        float* op = out + (size_t)ray * 3;
        op[0] = R; op[1] = G; op[2] = B;
    }
}

extern "C" void kernel_launch(void* const* d_in, const int* in_sizes, int n_in,
                              void* d_out, int out_size, void* d_ws, size_t ws_size,
                              hipStream_t stream) {
    const float* rays      = (const float*)d_in[0];
    const float* sigmas    = (const float*)d_in[1];
    const float* rgbs      = (const float*)d_in[2];
    const float* center    = (const float*)d_in[3];
    const float* half_size = (const float*)d_in[4];
    float* out = (float*)d_out;

    const int threads = 256;                     // 4 waves -> 4 rays per block
    const int blocks  = N_RAYS / 4;              // 16384
    ngp_render_kernel<<<blocks, threads, 0, stream>>>(
        rays, sigmas, rgbs, center, half_size, out);
}

// Round 2
// 28.719 us; speedup vs baseline: 1.5451x; 1.5451x over previous
//
#include <hip/hip_runtime.h>
#include <math.h>

#define N_RAYS 65536
#define N_SAMPLES 256
#define T_THRESHOLD 1e-4f
#define NEAR_DISTANCE 0.01f

// One 64-lane wave per ray. Lane l handles samples [4l, 4l+4).
// Rays that miss the AABB contribute exactly zero -> skip their
// sigma/rgb reads entirely (wave-uniform early exit).
__global__ __launch_bounds__(256) void ngp_render_kernel(
    const float* __restrict__ rays,      // [N_RAYS, 6]
    const float* __restrict__ sigmas,    // [N_RAYS, N_SAMPLES]
    const float* __restrict__ rgbs,      // [N_RAYS, N_SAMPLES, 3]
    const float* __restrict__ center,    // [3]
    const float* __restrict__ half_size, // [3]
    float* __restrict__ out)             // [N_RAYS, 3]
{
    const int gtid = blockIdx.x * blockDim.x + threadIdx.x;
    const int ray  = gtid >> 6;          // wave index == ray index
    const int lane = threadIdx.x & 63;
    if (ray >= N_RAYS) return;

    // ---- ray setup: every lane computes the same (broadcast loads) ----
    const float* rp = rays + (size_t)ray * 6;
    float o[3] = { rp[0], rp[1], rp[2] };
    float d[3] = { rp[3], rp[4], rp[5] };
    float inv_norm = 1.0f / (sqrtf(d[0]*d[0] + d[1]*d[1] + d[2]*d[2]) + 1e-8f);
    d[0] *= inv_norm; d[1] *= inv_norm; d[2] *= inv_norm;

    float tmin = -INFINITY, tmax = INFINITY;
    #pragma unroll
    for (int a = 0; a < 3; ++a) {
        float da  = (fabsf(d[a]) > 1e-8f) ? d[a] : 1e-8f;
        float inv = 1.0f / da;
        float t1  = (center[a] - half_size[a] - o[a]) * inv;
        float t2  = (center[a] + half_size[a] - o[a]) * inv;
        tmin = fmaxf(tmin, fminf(t1, t2));
        tmax = fminf(tmax, fmaxf(t1, t2));
    }
    const bool hit = tmax > fmaxf(tmin, 0.0f);

    // ---- miss: output is exactly zero; skip all sigma/rgb traffic ----
    if (!hit) {
        if (lane == 0) {
            float* op = out + (size_t)ray * 3;
            op[0] = 0.0f; op[1] = 0.0f; op[2] = 0.0f;
        }
        return;
    }

    float near = fmaxf(tmin, 0.0f);
    if (near < NEAR_DISTANCE) near = NEAR_DISTANCE;
    const float far   = tmax;
    const float delta = (far - near) * (1.0f / (float)N_SAMPLES);

    // ---- sigma * delta, local prefix over 4 samples ----
    const float4 sg = *reinterpret_cast<const float4*>(
        sigmas + (size_t)ray * N_SAMPLES + lane * 4);
    const float sd0 = sg.x * delta;
    const float sd1 = sg.y * delta;
    const float sd2 = sg.z * delta;
    const float sd3 = sg.w * delta;
    const float p0 = sd0;
    const float p1 = p0 + sd1;
    const float p2 = p1 + sd2;
    const float p3 = p2 + sd3;        // lane total

    // ---- wave-inclusive scan of lane totals (6 shfl_up steps) ----
    float incl = p3;
    #pragma unroll
    for (int off = 1; off < 64; off <<= 1) {
        float v = __shfl_up(incl, off, 64);
        if (lane >= off) incl += v;
    }
    const float excl = incl - p3;     // exclusive prefix entering this lane

    // ---- transmittance, alpha, weights ----
    const float T0 = expf(-excl);
    const float T1 = expf(-(excl + p0));
    const float T2 = expf(-(excl + p1));
    const float T3 = expf(-(excl + p2));
    const float a0 = 1.0f - expf(-sd0);
    const float a1 = 1.0f - expf(-sd1);
    const float a2 = 1.0f - expf(-sd2);
    const float a3 = 1.0f - expf(-sd3);
    const float ws0 = (T0 >= T_THRESHOLD) ? a0 * T0 : 0.0f;
    const float ws1 = (T1 >= T_THRESHOLD) ? a1 * T1 : 0.0f;
    const float ws2 = (T2 >= T_THRESHOLD) ? a2 * T2 : 0.0f;
    const float ws3 = (T3 >= T_THRESHOLD) ? a3 * T3 : 0.0f;

    // ---- rgbs: 48 contiguous bytes per lane, 3 aligned float4 loads ----
    const float* rb = rgbs + (size_t)ray * N_SAMPLES * 3 + (size_t)lane * 12;
    const float4 r0 = *reinterpret_cast<const float4*>(rb + 0);
    const float4 r1 = *reinterpret_cast<const float4*>(rb + 4);
    const float4 r2 = *reinterpret_cast<const float4*>(rb + 8);
    // sample 4l+0 -> (r0.x, r0.y, r0.z)
    // sample 4l+1 -> (r0.w, r1.x, r1.y)
    // sample 4l+2 -> (r1.z, r1.w, r2.x)
    // sample 4l+3 -> (r2.y, r2.z, r2.w)
    float R = ws0 * r0.x + ws1 * r0.w + ws2 * r1.z + ws3 * r2.y;
    float G = ws0 * r0.y + ws1 * r1.x + ws2 * r1.w + ws3 * r2.z;
    float B = ws0 * r0.z + ws1 * r1.y + ws2 * r2.x + ws3 * r2.w;

    // ---- wave reduce ----
    #pragma unroll
    for (int off = 32; off > 0; off >>= 1) {
        R += __shfl_xor(R, off, 64);
        G += __shfl_xor(G, off, 64);
        B += __shfl_xor(B, off, 64);
    }
    if (lane == 0) {
        float* op = out + (size_t)ray * 3;
        op[0] = R; op[1] = G; op[2] = B;
    }
}

extern "C" void kernel_launch(void* const* d_in, const int* in_sizes, int n_in,
                              void* d_out, int out_size, void* d_ws, size_t ws_size,
                              hipStream_t stream) {
    const float* rays      = (const float*)d_in[0];
    const float* sigmas    = (const float*)d_in[1];
    const float* rgbs      = (const float*)d_in[2];
    const float* center    = (const float*)d_in[3];
    const float* half_size = (const float*)d_in[4];
    float* out = (float*)d_out;

    const int threads = 256;                     // 4 waves -> 4 rays per block
    const int blocks  = N_RAYS / 4;              // 16384
    ngp_render_kernel<<<blocks, threads, 0, stream>>>(
        rays, sigmas, rgbs, center, half_size, out);
}